// Round 3
// baseline (233.798 us; speedup 1.0000x reference)
//
#include <hip/hip_runtime.h>
#include <math.h>

#define BUF_SIZE 1000
// Mirror the reference's constants exactly (LN2 truncated to 0.693147).
#define TARGET_LOG_MEAN 7.6438561897747395f            // float(np.log2(200.0))
#define TARGET_LOG_STD  (40.0f / (200.0f * 0.693147f)) // 0.288538...

// ---------------------------------------------------------------------------
// Fused kernel. Every block independently (and deterministically identically)
// computes the mean/std of the last min(1000, n_valid) valid log2-pitches by
// scanning the tail backward (~2 chunks of 1024 elements, L2-broadcast across
// blocks), then streams the elementwise transform with float4 accesses.
// This removes the serial 1-block stats kernel + its launch from the critical
// path: the stats cost is paid once, in parallel, by all blocks.
// NOTE: plain float4 loads/stores only — no nontemporal builtins (suspected
// container-killer in rounds 1-2).
// ---------------------------------------------------------------------------
__global__ __launch_bounds__(256) void fused_kernel(
    const float* __restrict__ pitch, float* __restrict__ out, long long n) {
    const int tid  = threadIdx.x;
    const int lane = tid & 63;
    const int wid  = tid >> 6;          // 0..3 (4 waves per block)

    __shared__ int    s_wtot[4];
    __shared__ double s_red[8];
    __shared__ float  s_sb[2];          // [0]=scale, [1]=bias

    // ---- Phase 1: redundant per-block stats from the tail ------------------
    double sum = 0.0, sumsq = 0.0;
    long long count_so_far = 0;

    // bits for lanes strictly above mine (within my wave)
    const unsigned long long above =
        (lane == 63) ? 0ULL : (~0ULL << (lane + 1));

    const long long nchunks = (n + 1023) >> 10;   // 1024-element chunks
    for (long long c = nchunks - 1; c >= 0; --c) {
        const long long base = (c << 10) + (long long)tid * 4;
        float v[4];
        int valid[4];
#pragma unroll
        for (int j = 0; j < 4; ++j) {
            const long long idx = base + j;
            const float p = (idx < n) ? pitch[idx] : 0.0f;
            v[j] = p;
            valid[j] = (p > 0.0f) ? 1 : 0;
        }

        // Ballot-based suffix count: all 4 j-positions of a higher thread are
        // after all positions of this thread, so within-wave suffix is the
        // popcount of higher lanes summed over the 4 ballots.
        int suff_wave = 0;   // valid elems in higher lanes of my wave
        int wtot = 0;        // valid elems in my wave (uniform)
#pragma unroll
        for (int j = 0; j < 4; ++j) {
            const unsigned long long m = __ballot(valid[j]);
            suff_wave += __popcll(m & above);
            wtot      += __popcll(m);
        }
        if (lane == 0) s_wtot[wid] = wtot;
        __syncthreads();
        int suff_after = suff_wave;      // + valid elems in higher waves
        int total = 0;
#pragma unroll
        for (int w = 0; w < 4; ++w) {
            const int t = s_wtot[w];
            total += t;
            if (w > wid) suff_after += t;
        }

        // Walk my 4 elements newest-to-oldest, assigning global reverse ranks.
        int r = 0;
#pragma unroll
        for (int j = 3; j >= 0; --j) {
            if (valid[j]) {
                const long long rev = count_so_far + suff_after + r;
                if (rev < BUF_SIZE) {
                    const double lp = (double)__log2f(v[j]);
                    sum   += lp;
                    sumsq += lp * lp;
                }
                r++;
            }
        }
        count_so_far += total;
        __syncthreads();                 // s_wtot reused next iteration
        if (count_so_far >= BUF_SIZE) break;   // uniform across block
    }

    // Wave-level double reduction, then 4-way LDS combine.
#pragma unroll
    for (int off = 32; off > 0; off >>= 1) {
        sum   += __shfl_down(sum,   off, 64);
        sumsq += __shfl_down(sumsq, off, 64);
    }
    if (lane == 0) { s_red[wid] = sum; s_red[4 + wid] = sumsq; }
    __syncthreads();
    if (tid == 0) {
        const double tsum   = s_red[0] + s_red[1] + s_red[2] + s_red[3];
        const double tsumsq = s_red[4] + s_red[5] + s_red[6] + s_red[7];
        const long long count =
            (count_so_far < BUF_SIZE) ? count_so_far : BUF_SIZE;
        float mean, stdv;
        if (count == 0) {
            mean = 0.0f;
            stdv = 1.0f;
        } else {
            mean = (float)(tsum / (double)count);
            if (count > 1) {
                double var = (tsumsq - tsum * tsum / (double)count) /
                             (double)(count - 1);
                if (var < 0.0) var = 0.0;
                stdv = (float)sqrt(var);
            } else {
                stdv = 1.0f;
            }
        }
        if (stdv < 1e-7f) stdv = 1e-7f;
        const float scale = TARGET_LOG_STD / stdv;
        s_sb[0] = scale;
        s_sb[1] = TARGET_LOG_MEAN - mean * scale;
    }
    __syncthreads();
    const float scale = s_sb[0];
    const float bias  = s_sb[1];

    // ---- Phase 2: streaming elementwise transform --------------------------
    // out = p>0 ? exp2(log2(p)*scale + bias) : 0
    const float4* __restrict__ in4  = (const float4*)pitch;
    float4* __restrict__       out4 = (float4*)out;
    const long long n4     = n >> 2;
    const long long gid    = (long long)blockIdx.x * blockDim.x + tid;
    const long long stride = (long long)gridDim.x * blockDim.x;

    for (long long k = gid; k < n4; k += stride) {
        const float4 p = in4[k];
        float4 o;
        o.x = (p.x > 0.0f) ? exp2f(fmaf(__log2f(p.x), scale, bias)) : 0.0f;
        o.y = (p.y > 0.0f) ? exp2f(fmaf(__log2f(p.y), scale, bias)) : 0.0f;
        o.z = (p.z > 0.0f) ? exp2f(fmaf(__log2f(p.z), scale, bias)) : 0.0f;
        o.w = (p.w > 0.0f) ? exp2f(fmaf(__log2f(p.w), scale, bias)) : 0.0f;
        out4[k] = o;
    }

    // Scalar tail (n not divisible by 4).
    const long long tail_start = n4 << 2;
    for (long long k = tail_start + gid; k < n; k += stride) {
        const float p = pitch[k];
        out[k] = (p > 0.0f) ? exp2f(fmaf(__log2f(p), scale, bias)) : 0.0f;
    }
}

extern "C" void kernel_launch(void* const* d_in, const int* in_sizes, int n_in,
                              void* d_out, int out_size, void* d_ws, size_t ws_size,
                              hipStream_t stream) {
    const float* pitch = (const float*)d_in[0];
    float* out = (float*)d_out;
    const long long n = (long long)in_sizes[0];

    // 2048 blocks x 256 threads: fully co-resident (8 blocks/CU), grid-stride
    // covers n4 = n/4 float4's in ~16 iterations per thread at n = 2^25.
    int blocks = 2048;
    const long long n4 = n / 4;
    if ((long long)blocks * 256 > n4 + 255) {
        blocks = (int)((n4 + 255) / 256);
        if (blocks < 1) blocks = 1;
    }
    fused_kernel<<<blocks, 256, 0, stream>>>(pitch, out, n);
}

// Round 4
// 229.129 us; speedup vs baseline: 1.0204x; 1.0204x over previous
//
#include <hip/hip_runtime.h>
#include <math.h>

#define BUF_SIZE 1000
// Mirror the reference's constants exactly (LN2 truncated to 0.693147).
#define TARGET_LOG_MEAN 7.6438561897747395f            // float(np.log2(200.0))
#define TARGET_LOG_STD  (40.0f / (200.0f * 0.693147f)) // 0.288538...

// ---------------------------------------------------------------------------
// Fused kernel, round 4: attack the latency-bound streaming loop seen in
// round 3 (hbm 30%, VALU 17%, occ 67% => MLP-starved).
//  - Phase 2 processes 4 float4/thread/iter with a 1-deep software pipeline
//    (prefetch next iter's 4 loads before computing current) => ~8 loads in
//    flight per wave instead of ~2.
//  - First streaming iteration is prefetched BEFORE the stats phase so HBM
//    streaming starts immediately (stats convoy hidden under it).
//  - Stats phase uses 2048-elem chunks (8/thread, float4 loads): typically a
//    single chunk (~1638 valid >= 1000) instead of two.
// ---------------------------------------------------------------------------
__global__ __launch_bounds__(256, 6) void fused_kernel(
    const float* __restrict__ pitch, float* __restrict__ out, long long n) {
    const int tid  = threadIdx.x;
    const int lane = tid & 63;
    const int wid  = tid >> 6;          // 0..3 (4 waves per block)

    __shared__ int    s_wtot[4];
    __shared__ double s_red[8];
    __shared__ float  s_sb[2];          // [0]=scale, [1]=bias

    const float4* __restrict__ in4  = (const float4*)pitch;
    float4* __restrict__       out4 = (float4*)out;
    const long long n4      = n >> 2;
    const long long CHUNK4  = 1024;                         // float4 per block-iter
    const long long gstride = (long long)gridDim.x * CHUNK4;
    const long long kbase   = (long long)blockIdx.x * CHUNK4 + tid;

    // ---- Prefetch streaming iteration 0 (overlaps the stats phase) --------
    float4 a0 = {0,0,0,0}, a1 = {0,0,0,0}, a2 = {0,0,0,0}, a3 = {0,0,0,0};
    if (kbase < n4)       a0 = in4[kbase];
    if (kbase + 256 < n4) a1 = in4[kbase + 256];
    if (kbase + 512 < n4) a2 = in4[kbase + 512];
    if (kbase + 768 < n4) a3 = in4[kbase + 768];

    // ---- Phase 1: redundant per-block stats from the tail ------------------
    double sum = 0.0, sumsq = 0.0;
    long long count_so_far = 0;

    // bits for lanes strictly above mine (within my wave)
    const unsigned long long above =
        (lane == 63) ? 0ULL : (~0ULL << (lane + 1));

    const long long nchunks = (n + 2047) >> 11;   // 2048-element chunks
    for (long long c = nchunks - 1; c >= 0; --c) {
        const long long base = (c << 11) + (long long)tid * 8;
        float v[8];
        if (base + 8 <= n) {
            // base is a multiple of 8 -> float4-aligned
            const float4 x = in4[(base >> 2)];
            const float4 y = in4[(base >> 2) + 1];
            v[0] = x.x; v[1] = x.y; v[2] = x.z; v[3] = x.w;
            v[4] = y.x; v[5] = y.y; v[6] = y.z; v[7] = y.w;
        } else {
#pragma unroll
            for (int j = 0; j < 8; ++j) {
                const long long idx = base + j;
                v[j] = (idx < n) ? pitch[idx] : 0.0f;
            }
        }

        int valid[8];
        int suff_wave = 0;   // valid elems in higher lanes of my wave
        int wtot = 0;        // valid elems in my wave (uniform)
#pragma unroll
        for (int j = 0; j < 8; ++j) {
            valid[j] = (v[j] > 0.0f) ? 1 : 0;
            const unsigned long long m = __ballot(valid[j]);
            suff_wave += __popcll(m & above);
            wtot      += __popcll(m);
        }
        if (lane == 0) s_wtot[wid] = wtot;
        __syncthreads();
        int suff_after = suff_wave;      // + valid elems in higher waves
        int total = 0;
#pragma unroll
        for (int w = 0; w < 4; ++w) {
            const int t = s_wtot[w];
            total += t;
            if (w > wid) suff_after += t;
        }

        // Walk my 8 elements newest-to-oldest, assigning global reverse ranks.
        int r = 0;
#pragma unroll
        for (int j = 7; j >= 0; --j) {
            if (valid[j]) {
                const long long rev = count_so_far + suff_after + r;
                if (rev < BUF_SIZE) {
                    const double lp = (double)__log2f(v[j]);
                    sum   += lp;
                    sumsq += lp * lp;
                }
                r++;
            }
        }
        count_so_far += total;
        __syncthreads();                 // s_wtot reused next iteration
        if (count_so_far >= BUF_SIZE) break;   // uniform across block
    }

    // Wave-level double reduction, then 4-way LDS combine.
#pragma unroll
    for (int off = 32; off > 0; off >>= 1) {
        sum   += __shfl_down(sum,   off, 64);
        sumsq += __shfl_down(sumsq, off, 64);
    }
    if (lane == 0) { s_red[wid] = sum; s_red[4 + wid] = sumsq; }
    __syncthreads();
    if (tid == 0) {
        const double tsum   = s_red[0] + s_red[1] + s_red[2] + s_red[3];
        const double tsumsq = s_red[4] + s_red[5] + s_red[6] + s_red[7];
        const long long count =
            (count_so_far < BUF_SIZE) ? count_so_far : BUF_SIZE;
        float mean, stdv;
        if (count == 0) {
            mean = 0.0f;
            stdv = 1.0f;
        } else {
            mean = (float)(tsum / (double)count);
            if (count > 1) {
                double var = (tsumsq - tsum * tsum / (double)count) /
                             (double)(count - 1);
                if (var < 0.0) var = 0.0;
                stdv = (float)sqrt(var);
            } else {
                stdv = 1.0f;
            }
        }
        if (stdv < 1e-7f) stdv = 1e-7f;
        const float scale = TARGET_LOG_STD / stdv;
        s_sb[0] = scale;
        s_sb[1] = TARGET_LOG_MEAN - mean * scale;
    }
    __syncthreads();
    const float scale = s_sb[0];
    const float bias  = s_sb[1];

    // ---- Phase 2: streaming transform, 4x unroll + 1-deep pipeline ---------
    long long k = kbase;
    while (k < n4) {
        const long long kn = k + gstride;
        // Issue next iteration's loads first (up to 8 loads in flight).
        float4 b0 = {0,0,0,0}, b1 = {0,0,0,0}, b2 = {0,0,0,0}, b3 = {0,0,0,0};
        if (kn < n4)       b0 = in4[kn];
        if (kn + 256 < n4) b1 = in4[kn + 256];
        if (kn + 512 < n4) b2 = in4[kn + 512];
        if (kn + 768 < n4) b3 = in4[kn + 768];

        float4 o0, o1, o2, o3;
        o0.x = (a0.x > 0.0f) ? exp2f(fmaf(__log2f(a0.x), scale, bias)) : 0.0f;
        o0.y = (a0.y > 0.0f) ? exp2f(fmaf(__log2f(a0.y), scale, bias)) : 0.0f;
        o0.z = (a0.z > 0.0f) ? exp2f(fmaf(__log2f(a0.z), scale, bias)) : 0.0f;
        o0.w = (a0.w > 0.0f) ? exp2f(fmaf(__log2f(a0.w), scale, bias)) : 0.0f;
        o1.x = (a1.x > 0.0f) ? exp2f(fmaf(__log2f(a1.x), scale, bias)) : 0.0f;
        o1.y = (a1.y > 0.0f) ? exp2f(fmaf(__log2f(a1.y), scale, bias)) : 0.0f;
        o1.z = (a1.z > 0.0f) ? exp2f(fmaf(__log2f(a1.z), scale, bias)) : 0.0f;
        o1.w = (a1.w > 0.0f) ? exp2f(fmaf(__log2f(a1.w), scale, bias)) : 0.0f;
        o2.x = (a2.x > 0.0f) ? exp2f(fmaf(__log2f(a2.x), scale, bias)) : 0.0f;
        o2.y = (a2.y > 0.0f) ? exp2f(fmaf(__log2f(a2.y), scale, bias)) : 0.0f;
        o2.z = (a2.z > 0.0f) ? exp2f(fmaf(__log2f(a2.z), scale, bias)) : 0.0f;
        o2.w = (a2.w > 0.0f) ? exp2f(fmaf(__log2f(a2.w), scale, bias)) : 0.0f;
        o3.x = (a3.x > 0.0f) ? exp2f(fmaf(__log2f(a3.x), scale, bias)) : 0.0f;
        o3.y = (a3.y > 0.0f) ? exp2f(fmaf(__log2f(a3.y), scale, bias)) : 0.0f;
        o3.z = (a3.z > 0.0f) ? exp2f(fmaf(__log2f(a3.z), scale, bias)) : 0.0f;
        o3.w = (a3.w > 0.0f) ? exp2f(fmaf(__log2f(a3.w), scale, bias)) : 0.0f;

        out4[k] = o0;                          // k < n4 by loop condition
        if (k + 256 < n4) out4[k + 256] = o1;
        if (k + 512 < n4) out4[k + 512] = o2;
        if (k + 768 < n4) out4[k + 768] = o3;

        a0 = b0; a1 = b1; a2 = b2; a3 = b3;
        k = kn;
    }

    // Scalar tail (n not divisible by 4).
    const long long tail_start = n4 << 2;
    const long long gid     = (long long)blockIdx.x * 256 + tid;
    const long long tstride = (long long)gridDim.x * 256;
    for (long long t = tail_start + gid; t < n; t += tstride) {
        const float p = pitch[t];
        out[t] = (p > 0.0f) ? exp2f(fmaf(__log2f(p), scale, bias)) : 0.0f;
    }
}

extern "C" void kernel_launch(void* const* d_in, const int* in_sizes, int n_in,
                              void* d_out, int out_size, void* d_ws, size_t ws_size,
                              hipStream_t stream) {
    const float* pitch = (const float*)d_in[0];
    float* out = (float*)d_out;
    const long long n = (long long)in_sizes[0];

    // 2048 blocks x 256 threads, 1024 float4 per block-iteration:
    // n4 = 2^23 float4 -> 4 pipelined iterations per thread. All blocks
    // co-resident, so the redundant stats phase is paid once, in parallel.
    const long long n4 = n / 4;
    long long want = (n4 + 1023) / 1024;
    int blocks = (int)((want < 2048) ? want : 2048);
    if (blocks < 1) blocks = 1;
    fused_kernel<<<blocks, 256, 0, stream>>>(pitch, out, n);
}

// Round 6
// 225.081 us; speedup vs baseline: 1.0387x; 1.0180x over previous
//
#include <hip/hip_runtime.h>
#include <math.h>

#define BUF_SIZE 1000
// Mirror the reference's constants exactly (LN2 truncated to 0.693147).
#define TARGET_LOG_MEAN 7.6438561897747395f            // float(np.log2(200.0))
#define TARGET_LOG_STD  (40.0f / (200.0f * 0.693147f)) // 0.288538...

// ---------------------------------------------------------------------------
// Round 6. Two-kernel structure (round 0's, which measured 224.8 total — the
// best so far) with ONE change: the stats kernel's Hillis-Steele scan
// (2 chunks x 17 barriers) is replaced by the ballot/popcount suffix-rank
// version validated inside rounds 3-4 (typically 1 chunk, 2 barriers).
// The apply kernel is byte-identical to round 0's. No nontemporal builtins:
// 3/3 container failures correlate with that construct (rounds 1,2,5).
// ---------------------------------------------------------------------------

// Kernel 1: stats of the last min(1000, n_valid) valid log2-pitches.
// Single block, 256 threads, backward scan in 2048-element chunks
// (8 elems/thread via two float4 loads). ~3-5 us serial.
__global__ __launch_bounds__(256) void stats_kernel(
    const float* __restrict__ pitch, long long n, float* __restrict__ stats) {
    const int tid  = threadIdx.x;
    const int lane = tid & 63;
    const int wid  = tid >> 6;          // 0..3 (4 waves)

    __shared__ int    s_wtot[4];
    __shared__ double s_red[8];

    const float4* __restrict__ in4 = (const float4*)pitch;

    double sum = 0.0, sumsq = 0.0;
    long long count_so_far = 0;

    // bits for lanes strictly above mine (within my wave)
    const unsigned long long above =
        (lane == 63) ? 0ULL : (~0ULL << (lane + 1));

    const long long nchunks = (n + 2047) >> 11;   // 2048-element chunks
    for (long long c = nchunks - 1; c >= 0; --c) {
        const long long base = (c << 11) + (long long)tid * 8;
        float v[8];
        if (base + 8 <= n) {
            // base is a multiple of 8 -> float4-aligned
            const float4 x = in4[(base >> 2)];
            const float4 y = in4[(base >> 2) + 1];
            v[0] = x.x; v[1] = x.y; v[2] = x.z; v[3] = x.w;
            v[4] = y.x; v[5] = y.y; v[6] = y.z; v[7] = y.w;
        } else {
#pragma unroll
            for (int j = 0; j < 8; ++j) {
                const long long idx = base + j;
                v[j] = (idx < n) ? pitch[idx] : 0.0f;
            }
        }

        int valid[8];
        int suff_wave = 0;   // valid elems in higher lanes of my wave
        int wtot = 0;        // valid elems in my wave (wave-uniform)
#pragma unroll
        for (int j = 0; j < 8; ++j) {
            valid[j] = (v[j] > 0.0f) ? 1 : 0;
            const unsigned long long m = __ballot(valid[j]);
            suff_wave += __popcll(m & above);
            wtot      += __popcll(m);
        }
        if (lane == 0) s_wtot[wid] = wtot;
        __syncthreads();
        int suff_after = suff_wave;      // + valid elems in higher waves
        int total = 0;
#pragma unroll
        for (int w = 0; w < 4; ++w) {
            const int t = s_wtot[w];
            total += t;
            if (w > wid) suff_after += t;
        }

        // Walk my 8 elements newest-to-oldest, assigning global reverse ranks.
        int r = 0;
#pragma unroll
        for (int j = 7; j >= 0; --j) {
            if (valid[j]) {
                const long long rev = count_so_far + suff_after + r;
                if (rev < BUF_SIZE) {
                    const double lp = (double)__log2f(v[j]);
                    sum   += lp;
                    sumsq += lp * lp;
                }
                r++;
            }
        }
        count_so_far += total;
        __syncthreads();                 // s_wtot reused next iteration
        if (count_so_far >= BUF_SIZE) break;   // uniform across block
    }

    // Wave-level double reduction, then 4-way LDS combine.
#pragma unroll
    for (int off = 32; off > 0; off >>= 1) {
        sum   += __shfl_down(sum,   off, 64);
        sumsq += __shfl_down(sumsq, off, 64);
    }
    if (lane == 0) { s_red[wid] = sum; s_red[4 + wid] = sumsq; }
    __syncthreads();
    if (tid == 0) {
        const double tsum   = s_red[0] + s_red[1] + s_red[2] + s_red[3];
        const double tsumsq = s_red[4] + s_red[5] + s_red[6] + s_red[7];
        const long long count =
            (count_so_far < BUF_SIZE) ? count_so_far : BUF_SIZE;
        float mean, stdv;
        if (count == 0) {
            mean = 0.0f;
            stdv = 1.0f;
        } else {
            mean = (float)(tsum / (double)count);
            if (count > 1) {
                double var = (tsumsq - tsum * tsum / (double)count) /
                             (double)(count - 1);
                if (var < 0.0) var = 0.0;
                stdv = (float)sqrt(var);
            } else {
                stdv = 1.0f;
            }
        }
        if (stdv < 1e-7f) stdv = 1e-7f;
        const float scale = TARGET_LOG_STD / stdv;
        stats[0] = scale;
        stats[1] = TARGET_LOG_MEAN - mean * scale;
    }
}

// Kernel 2: streaming elementwise transform — byte-identical to round 0's
// (one-shot blocks, 1 float4/thread at this problem size; block churn was
// empirically the fastest streaming mode: ~4.9 TB/s logical vs ~3.4 for
// persistent grid-stride).
__global__ void apply_kernel(const float4* __restrict__ in4,
                             float4* __restrict__ out4, long long n4,
                             const float* __restrict__ pitch,
                             float* __restrict__ out, long long n,
                             const float* __restrict__ stats) {
    const float scale = stats[0];
    const float bias = stats[1];
    const long long gid = (long long)blockIdx.x * blockDim.x + threadIdx.x;
    const long long stride = (long long)gridDim.x * blockDim.x;

    for (long long k = gid; k < n4; k += stride) {
        const float4 p = in4[k];
        float4 o;
        o.x = (p.x > 0.0f) ? exp2f(fmaf(__log2f(p.x), scale, bias)) : 0.0f;
        o.y = (p.y > 0.0f) ? exp2f(fmaf(__log2f(p.y), scale, bias)) : 0.0f;
        o.z = (p.z > 0.0f) ? exp2f(fmaf(__log2f(p.z), scale, bias)) : 0.0f;
        o.w = (p.w > 0.0f) ? exp2f(fmaf(__log2f(p.w), scale, bias)) : 0.0f;
        out4[k] = o;
    }

    // Scalar tail (n not divisible by 4).
    const long long tail_start = n4 * 4;
    for (long long k = tail_start + gid; k < n; k += stride) {
        const float p = pitch[k];
        out[k] = (p > 0.0f) ? exp2f(fmaf(__log2f(p), scale, bias)) : 0.0f;
    }
}

extern "C" void kernel_launch(void* const* d_in, const int* in_sizes, int n_in,
                              void* d_out, int out_size, void* d_ws, size_t ws_size,
                              hipStream_t stream) {
    const float* pitch = (const float*)d_in[0];
    float* out = (float*)d_out;
    const long long n = (long long)in_sizes[0];
    float* stats = (float*)d_ws;   // [0]=scale, [1]=bias

    stats_kernel<<<1, 256, 0, stream>>>(pitch, n, stats);

    const long long n4 = n / 4;
    int blocks = (int)((n4 + 255) / 256);
    if (blocks > 32768) blocks = 32768;   // grid-stride covers the rest
    if (blocks < 1) blocks = 1;
    apply_kernel<<<blocks, 256, 0, stream>>>((const float4*)pitch, (float4*)out,
                                             n4, pitch, out, n, stats);
}